// Round 3
// baseline (219.403 us; speedup 1.0000x reference)
//
#include <hip/hip_runtime.h>
#include <hip/hip_bf16.h>

// ChannelDense: y[b,n,o] = tanh( sum_i x[b,n,i] * W[c[n],o,i] + bias[c[n],o] ) + x[b,n,o]
// B=128, N=2048, IN=OUT=256, 64 channels.
// One wg per n: GEMM M=256(out) x N=128(batch) x K=256(in)  [operands SWAPPED vs R1
// so D rows = o -> float4 stores]. bf16 MFMA, f32 accum.
// sA: x-tile [kt=8][row=128][64B] bf16, swizzled (row&7)<<4  (64KB, also residual src)
// sB: W-slice [o=256][64B] bf16, swizzled (o&7)<<4           (16KB)
// W staging async-split: global->reg 1 K-iter ahead; cvt+ds_write after MFMA.
// R3 fix: sB second 16B write address must be (linear+16)^swz, not (linear^swz)+16
// (ADD after XOR breaks bijectivity for odd o -> unwritten slots -> NaN).

#define B_SZ  128
#define N_SZ  2048

typedef __attribute__((ext_vector_type(8))) __bf16 bf16x8;
typedef __attribute__((ext_vector_type(4))) float  f32x4;

__device__ __forceinline__ unsigned f2bf1(float f) {
    union { float f; unsigned u; } v; v.f = f;
    return (v.u + 0x7fffu + ((v.u >> 16) & 1u)) >> 16;   // RNE
}
__device__ __forceinline__ int pack2(float lo, float hi) {
    return (int)(f2bf1(lo) | (f2bf1(hi) << 16));
}
__device__ __forceinline__ float bf2f(unsigned u16) {
    union { unsigned u; float f; } v; v.u = u16 << 16;
    return v.f;
}
__device__ __forceinline__ float tanh_fast(float s) {
    float a = fabsf(s);
    float t = __expf(-2.0f * a);
    float r = (1.0f - t) * __builtin_amdgcn_rcpf(1.0f + t);
    return s < 0.0f ? -r : r;
}

__global__ __launch_bounds__(512, 4) void channel_dense_kernel(
    const float* __restrict__ x, const int* __restrict__ channels,
    const float* __restrict__ weight, const float* __restrict__ bias,
    float* __restrict__ y)
{
    __shared__ __align__(16) unsigned char smem[65536 + 16384];
    unsigned char* sA = smem;             // [8][128][64] bytes
    unsigned char* sB = smem + 65536;     // [256][64] bytes

    const int n   = blockIdx.x;
    const int tid = threadIdx.x;
    const int c   = channels[n];
    const float* wch = weight + (size_t)c * 65536;

    // ---- W async-stage state: each thread owns 16 floats of a 32-k slice ----
    const int bo = tid >> 1;               // 0..255 (out row)
    const int bh = tid & 1;                // which 16-float half
    const float* wbase = wch + bo * 256 + bh * 16;
    float4 w0, w1, w2, w3;
    #define WLOAD(kt) do { const float* p_ = wbase + (kt) * 32;             \
        w0 = *(const float4*)(p_);     w1 = *(const float4*)(p_ + 4);       \
        w2 = *(const float4*)(p_ + 8); w3 = *(const float4*)(p_ + 12); } while (0)

    const int sb_lin   = bo * 64 + bh * 32;
    const int sb_swz   = (bo & 7) << 4;
    const int sb_byte0 = (sb_lin)      ^ sb_swz;   // XOR applied to full linear addr
    const int sb_byte1 = (sb_lin + 16) ^ sb_swz;
    #define SB_WRITE() do {                                                 \
        int4 q0, q1;                                                        \
        q0.x = pack2(w0.x, w0.y); q0.y = pack2(w0.z, w0.w);                 \
        q0.z = pack2(w1.x, w1.y); q0.w = pack2(w1.z, w1.w);                 \
        q1.x = pack2(w2.x, w2.y); q1.y = pack2(w2.z, w2.w);                 \
        q1.z = pack2(w3.x, w3.y); q1.w = pack2(w3.z, w3.w);                 \
        *(int4*)(sB + sb_byte0) = q0;                                       \
        *(int4*)(sB + sb_byte1) = q1; } while (0)

    WLOAD(0);                              // issue earliest; latency hides under stage-A

    // ---- stage A: x[:, n, :] -> bf16 LDS [kt][row][64B] ----
    {
        const int row = tid >> 2;          // batch b
        const int sub = tid & 3;           // 64-float chunk
        const float* xrow = x + ((size_t)row * N_SZ + n) * 256 + sub * 64;
        const int swz = (row & 7) << 4;
        #pragma unroll
        for (int j = 0; j < 8; ++j) {
            float4 f0 = *(const float4*)(xrow + j * 8);
            float4 f1 = *(const float4*)(xrow + j * 8 + 4);
            int4 p;
            p.x = pack2(f0.x, f0.y); p.y = pack2(f0.z, f0.w);
            p.z = pack2(f1.x, f1.y); p.w = pack2(f1.z, f1.w);
            int byte = (sub * 2 + (j >> 2)) * 8192 + ((row * 64 + (j & 3) * 16) ^ swz);
            *(int4*)(sA + byte) = p;
        }
    }

    SB_WRITE();                            // sB <- k-slice 0 (waits on WLOAD(0))
    WLOAD(1);                              // prefetch slice 1
    __syncthreads();                       // sA + sB(0) visible

    // ---- MFMA main loop: D[o][b] ----
    const int lane = tid & 63;
    const int wv   = tid >> 6;
    const int wo   = wv & 3;               // o 64-block
    const int wb   = wv >> 2;              // b 64-block
    const int lr   = lane & 15;
    const int lg4  = lane >> 4;
    const int lane_part = ((lr * 64 + lg4 * 16) ^ ((lr & 7) << 4));
    const int wf_base = lane_part + wo * 4096;           // into sB
    const int xf_base = lane_part + wb * 4096;           // into sA (+= kt*8192)

    f32x4 acc[4][4] = {};

    #pragma unroll
    for (int kt = 0; kt < 8; ++kt) {
        bf16x8 wf[4], xf[4];
        #pragma unroll
        for (int mo = 0; mo < 4; ++mo)
            wf[mo] = *(const bf16x8*)(sB + wf_base + mo * 1024);
        #pragma unroll
        for (int nb = 0; nb < 4; ++nb)
            xf[nb] = *(const bf16x8*)(sA + xf_base + nb * 1024 + kt * 8192);
        #pragma unroll
        for (int mo = 0; mo < 4; ++mo)
            #pragma unroll
            for (int nb = 0; nb < 4; ++nb)
                acc[mo][nb] = __builtin_amdgcn_mfma_f32_16x16x32_bf16(wf[mo], xf[nb], acc[mo][nb], 0, 0, 0);

        if (kt < 7) {
            __syncthreads();               // all reads of sB(kt) done
            SB_WRITE();                    // sB <- kt+1 (regs loaded a full iter ago)
            if (kt < 6) WLOAD(kt + 2);     // prefetch next
            __syncthreads();               // sB(kt+1) visible
        }
    }

    // ---- epilogue: + bias, tanh, + residual, float4 stores ----
    const float* bch = bias + (size_t)c * 256;
    #pragma unroll
    for (int mo = 0; mo < 4; ++mo) {
        const int o0 = wo * 64 + mo * 16 + lg4 * 4;      // 4 consecutive o per thread
        const float4 bv = *(const float4*)(bch + o0);
        const int kt_r  = o0 >> 5;
        const int intra = (o0 & 31) * 2;
        #pragma unroll
        for (int nb = 0; nb < 4; ++nb) {
            const int b = wb * 64 + nb * 16 + lr;
            // residual x[b][n][o0..o0+3] from bf16 A-tile
            const int rbyte = kt_r * 8192 + ((b * 64 + intra) ^ ((b & 7) << 4));
            uint2 rv = *(const uint2*)(sA + rbyte);
            float4 out;
            out.x = tanh_fast(acc[mo][nb][0] + bv.x) + bf2f(rv.x & 0xffffu);
            out.y = tanh_fast(acc[mo][nb][1] + bv.y) + bf2f(rv.x >> 16);
            out.z = tanh_fast(acc[mo][nb][2] + bv.z) + bf2f(rv.y & 0xffffu);
            out.w = tanh_fast(acc[mo][nb][3] + bv.w) + bf2f(rv.y >> 16);
            *(float4*)(y + ((size_t)b * N_SZ + n) * 256 + o0) = out;
        }
    }
    #undef WLOAD
    #undef SB_WRITE
}

__global__ void channels_copy_kernel(const int* __restrict__ ch, float* __restrict__ out) {
    int i = blockIdx.x * 256 + threadIdx.x;
    if (i < N_SZ) out[i] = (float)ch[i];
}

extern "C" void kernel_launch(void* const* d_in, const int* in_sizes, int n_in,
                              void* d_out, int out_size, void* d_ws, size_t ws_size,
                              hipStream_t stream) {
    const float* x        = (const float*)d_in[0];
    const int*   channels = (const int*)d_in[1];
    const float* weight   = (const float*)d_in[2];
    const float* bias     = (const float*)d_in[3];
    float* y = (float*)d_out;

    channel_dense_kernel<<<dim3(N_SZ), dim3(512), 0, stream>>>(x, channels, weight, bias, y);
    channels_copy_kernel<<<dim3(N_SZ / 256), dim3(256), 0, stream>>>(
        channels, y + (size_t)B_SZ * N_SZ * 256);
}

// Round 4
// 181.544 us; speedup vs baseline: 1.2085x; 1.2085x over previous
//
#include <hip/hip_runtime.h>
#include <hip/hip_bf16.h>

// ChannelDense: y[b,n,o] = tanh( sum_i x[b,n,i] * W[c[n],o,i] + bias[c[n],o] ) + x[b,n,o]
// B=128, N=2048, IN=OUT=256, 64 channels.
//
// R4 structure (attacking the outstanding-request limit seen in R1-R3):
//  k0: counting-sort points by channel -> perm (W L2 locality via XCD-chunked map)
//  k1: convert W f32 -> bf16 into d_ws, PRE-SWIZZLED so linear global_load_lds
//      staging produces the XOR-swizzled LDS image (rule-21: swizzle source+read)
//  k2: main GEMM. One wg per (point, batch-half): M=256(out) x N=64(b) x K=256.
//      sA: x half-tile [8 kt][64 r][64B] bf16 (32KB, residual source)
//      sB: W slice dbuf [2][256 o][64B] bf16 (32KB), staged via global_load_lds
//      (width 16, async, counted by the end-of-iter barrier only).
//  k3: channels passthrough.

#define N_SZ 2048

typedef __attribute__((ext_vector_type(8))) __bf16 bf16x8;
typedef __attribute__((ext_vector_type(4))) float  f32x4;

__device__ __forceinline__ unsigned f2bf1(float f) {
    union { float f; unsigned u; } v; v.f = f;
    return (v.u + 0x7fffu + ((v.u >> 16) & 1u)) >> 16;   // RNE
}
__device__ __forceinline__ int pack2(float lo, float hi) {
    return (int)(f2bf1(lo) | (f2bf1(hi) << 16));
}
__device__ __forceinline__ float bf2f(unsigned u16) {
    union { unsigned u; float f; } v; v.u = u16 << 16;
    return v.f;
}
__device__ __forceinline__ float tanh_fast(float s) {
    float a = fabsf(s);
    float t = __expf(-2.0f * a);
    float r = (1.0f - t) * __builtin_amdgcn_rcpf(1.0f + t);
    return s < 0.0f ? -r : r;
}
__device__ __forceinline__ void gl_lds16(const void* g, void* l) {
    __builtin_amdgcn_global_load_lds(
        (const __attribute__((address_space(1))) unsigned int*)g,
        (__attribute__((address_space(3))) unsigned int*)l, 16, 0, 0);
}

// ---- k0: counting sort of 2048 points into 64 channel buckets ----
__global__ __launch_bounds__(1024) void sort_kernel(const int* __restrict__ channels,
                                                    int* __restrict__ perm) {
    __shared__ int cnt[64], off[64];
    const int t = threadIdx.x;
    if (t < 64) cnt[t] = 0;
    __syncthreads();
    const int n0 = t, n1 = t + 1024;
    const int c0 = channels[n0], c1 = channels[n1];
    atomicAdd(&cnt[c0], 1);
    atomicAdd(&cnt[c1], 1);
    __syncthreads();
    if (t == 0) { int s = 0; for (int i = 0; i < 64; ++i) { off[i] = s; s += cnt[i]; } }
    __syncthreads();
    int p0 = atomicAdd(&off[c0], 1); perm[p0] = n0;
    int p1 = atomicAdd(&off[c1], 1); perm[p1] = n1;
}

// ---- k1: W f32 -> bf16, pre-swizzled image for linear LDS staging ----
// ws image per channel: 8 slices of 16KB; slice kt holds W[c][o][kt*32..+32] at
// byte ((o*64 + (k%32)*2) ^ ((o&7)<<4)).
__global__ __launch_bounds__(256) void wconv_kernel(const float* __restrict__ w,
                                                    unsigned char* __restrict__ wsW) {
    const int t   = blockIdx.x * 256 + threadIdx.x;    // 524288 total (16B chunks)
    const int c   = t >> 13;
    const int rem = t & 8191;
    const int o   = rem >> 5;
    const int ch  = rem & 31;                           // 8-element chunk within k
    const int kt  = ch >> 2;
    const int j   = ch & 3;
    const float* src = w + ((((size_t)c << 8) | o) << 8) + (ch << 3);
    float4 f0 = *(const float4*)(src);
    float4 f1 = *(const float4*)(src + 4);
    int4 p;
    p.x = pack2(f0.x, f0.y); p.y = pack2(f0.z, f0.w);
    p.z = pack2(f1.x, f1.y); p.w = pack2(f1.z, f1.w);
    const int dst = (c << 17) + (kt << 14) + ((o * 64 + j * 16) ^ ((o & 7) << 4));
    *(int4*)(wsW + dst) = p;
}

// ---- k2: main GEMM ----
__global__ __launch_bounds__(256, 2) void channel_dense_kernel(
    const float* __restrict__ x, const int* __restrict__ channels,
    const int* __restrict__ perm, const unsigned char* __restrict__ wsW,
    const float* __restrict__ bias, float* __restrict__ y)
{
    __shared__ __align__(16) unsigned char sA[32768];        // [8][64][64B]
    __shared__ __align__(16) unsigned char sB[2][16384];     // [256][64B] dbuf

    const int g    = blockIdx.x;
    const int lg   = (g & 7) * 512 + (g >> 3);               // XCD-chunked remap
    const int n    = perm[lg >> 1];
    const int half = lg & 1;                                  // batch half
    const int tid  = threadIdx.x;
    const int c    = channels[n];
    const unsigned char* wc = wsW + ((size_t)c << 17);

    const int lane = tid & 63;
    const int wv   = tid >> 6;                               // 0..3

    // stage W slice kt into sB[buf]: 4 waves x 4 instrs x 1KB, fully linear copy
    #define STAGE_W(kt, buf) do {                                              \
        const unsigned char* s_ = wc + ((kt) << 14) + (wv << 12) + (lane << 4);\
        unsigned char* d_ = sB[buf] + (wv << 12);                              \
        gl_lds16(s_,        d_);                                               \
        gl_lds16(s_ + 1024, d_ + 1024);                                        \
        gl_lds16(s_ + 2048, d_ + 2048);                                        \
        gl_lds16(s_ + 3072, d_ + 3072); } while (0)

    STAGE_W(0, 0);                       // in flight under the whole A-stage

    // ---- A-stage: x[half*64 .. +64, n, :] -> bf16 LDS ----
    {
        const int r   = tid >> 2;        // local row 0..63
        const int sub = tid & 3;         // 64-float chunk
        const float* xr = x + ((size_t)(half * 64 + r) * N_SZ + n) * 256 + sub * 64;
        const int swz = (r & 7) << 4;
        #pragma unroll
        for (int j = 0; j < 8; ++j) {
            float4 f0 = *(const float4*)(xr + j * 8);
            float4 f1 = *(const float4*)(xr + j * 8 + 4);
            int4 p;
            p.x = pack2(f0.x, f0.y); p.y = pack2(f0.z, f0.w);
            p.z = pack2(f1.x, f1.y); p.w = pack2(f1.z, f1.w);
            const int byte = (sub * 2 + (j >> 2)) * 4096 + ((r * 64 + (j & 3) * 16) ^ swz);
            *(int4*)(sA + byte) = p;
        }
    }
    __syncthreads();                     // drains STAGE_W(0) + A-stage writes

    const int lr   = lane & 15;
    const int lg4  = lane >> 4;
    const int lanebyte = (lr * 64 + lg4 * 16) ^ ((lr & 7) << 4);

    f32x4 acc[4][4] = {};

    #pragma unroll
    for (int kt = 0; kt < 8; ++kt) {
        if (kt < 7) STAGE_W(kt + 1, (kt + 1) & 1);   // async, drained at barrier
        bf16x8 wf[4], xf[4];
        #pragma unroll
        for (int mo = 0; mo < 4; ++mo)
            wf[mo] = *(const bf16x8*)(sB[kt & 1] + (wv << 12) + (mo << 10) + lanebyte);
        #pragma unroll
        for (int nb = 0; nb < 4; ++nb)
            xf[nb] = *(const bf16x8*)(sA + (kt << 12) + (nb << 10) + lanebyte);
        #pragma unroll
        for (int mo = 0; mo < 4; ++mo)
            #pragma unroll
            for (int nb = 0; nb < 4; ++nb)
                acc[mo][nb] = __builtin_amdgcn_mfma_f32_16x16x32_bf16(wf[mo], xf[nb], acc[mo][nb], 0, 0, 0);
        __syncthreads();                 // sB[(kt+1)&1] staged + reads of sB[kt&1] done
    }

    // ---- epilogue: + bias, tanh, + residual, float4 stores ----
    const float* bch = bias + (size_t)c * 256;
    #pragma unroll
    for (int mo = 0; mo < 4; ++mo) {
        const int o0 = wv * 64 + mo * 16 + lg4 * 4;          // 4 consecutive o
        const float4 bv = *(const float4*)(bch + o0);
        const int kt_r  = o0 >> 5;
        const int intra = (o0 & 31) * 2;
        #pragma unroll
        for (int nb = 0; nb < 4; ++nb) {
            const int rl = nb * 16 + lr;                     // local b row
            const int b  = half * 64 + rl;
            const int rbyte = (kt_r << 12) + ((rl * 64 + intra) ^ ((rl & 7) << 4));
            uint2 rv = *(const uint2*)(sA + rbyte);
            float4 out;
            out.x = tanh_fast(acc[mo][nb][0] + bv.x) + bf2f(rv.x & 0xffffu);
            out.y = tanh_fast(acc[mo][nb][1] + bv.y) + bf2f(rv.x >> 16);
            out.z = tanh_fast(acc[mo][nb][2] + bv.z) + bf2f(rv.y & 0xffffu);
            out.w = tanh_fast(acc[mo][nb][3] + bv.w) + bf2f(rv.y >> 16);
            *(float4*)(y + ((size_t)b * N_SZ + n) * 256 + o0) = out;
        }
    }
    #undef STAGE_W
}

__global__ void channels_copy_kernel(const int* __restrict__ ch, float* __restrict__ out) {
    int i = blockIdx.x * 256 + threadIdx.x;
    if (i < N_SZ) out[i] = (float)ch[i];
}

extern "C" void kernel_launch(void* const* d_in, const int* in_sizes, int n_in,
                              void* d_out, int out_size, void* d_ws, size_t ws_size,
                              hipStream_t stream) {
    const float* x        = (const float*)d_in[0];
    const int*   channels = (const int*)d_in[1];
    const float* weight   = (const float*)d_in[2];
    const float* bias     = (const float*)d_in[3];
    float* y = (float*)d_out;

    unsigned char* wsW = (unsigned char*)d_ws;               // 8 MB bf16 W image
    int* perm = (int*)(wsW + (64u << 17));                   // + 8KB perm

    sort_kernel<<<dim3(1), dim3(1024), 0, stream>>>(channels, perm);
    wconv_kernel<<<dim3(2048), dim3(256), 0, stream>>>(weight, wsW);
    channel_dense_kernel<<<dim3(4096), dim3(256), 0, stream>>>(
        x, channels, perm, wsW, bias, y);
    channels_copy_kernel<<<dim3(N_SZ / 256), dim3(256), 0, stream>>>(
        channels, y + (size_t)128 * N_SZ * 256);
}